// Round 5
// baseline (193.834 us; speedup 1.0000x reference)
//
#include <hip/hip_runtime.h>
#include <math.h>

static constexpr int kM = 80;
static constexpr int kT = 4000;
static constexpr int kB = 64;
static constexpr int kLow = kM / 3;                 // 26
static constexpr int kHighStart = 2 * kM / 3;       // 53
static constexpr int kHighCount = kM - kHighStart;  // 27
static constexpr int kPhases = 2;                   // 32 b per phase: 41 MB, L3-resident
static constexpr int kBPhase = kB / kPhases;
#define EPSF 1e-6f
#define LOG2E 1.4426950408889634f

typedef float vfloat4 __attribute__((ext_vector_type(4)));
typedef float vfloat2 __attribute__((ext_vector_type(2)));

// HW transcendentals: v_exp_f32 computes 2^x, v_log_f32 computes log2(x)
__device__ __forceinline__ float hw_exp2(float x) { return __builtin_amdgcn_exp2f(x); }
__device__ __forceinline__ float hw_log2(float x) { return __builtin_amdgcn_logf(x); }

__device__ __forceinline__ float fast_sigmoid(float x) {
    return __builtin_amdgcn_rcpf(1.0f + hw_exp2(-x * LOG2E));
}

// ---------------- Kernel A: gate[b,t] from cross-channel reductions ----------
// Block = 256 thr (4 waves); wave w sums channels [20w,20w+20); lane = 4 cols
// via float4. Cross-wave reduce in LDS; wave 0 finalizes. grid (16, kBPhase).
__global__ __launch_bounds__(256) void gate_kernel(
    const float* __restrict__ mel,
    const float* __restrict__ gate_temp,
    float* __restrict__ gate,
    int b0)
{
    const int lane = threadIdx.x & 63;
    const int wid  = threadIdx.x >> 6;
    const int b    = b0 + blockIdx.y;
    const int t0   = blockIdx.x * 256 + lane * 4;
    const bool valid = (t0 < kT);

    const float* base = mel + (size_t)b * kM * kT + t0;

    vfloat4 slog = {0.f,0.f,0.f,0.f}, ssum = {0.f,0.f,0.f,0.f};
    vfloat4 slow = {0.f,0.f,0.f,0.f}, shigh = {0.f,0.f,0.f,0.f};

    const int m0 = wid * 20;
    if (valid) {
        #pragma unroll
        for (int j = 0; j < 20; ++j) {
            const int m = m0 + j;
            const vfloat4 v = *reinterpret_cast<const vfloat4*>(base + (size_t)m * kT);
            vfloat4 lg;
            lg.x = hw_log2(v.x + 1e-8f); lg.y = hw_log2(v.y + 1e-8f);
            lg.z = hw_log2(v.z + 1e-8f); lg.w = hw_log2(v.w + 1e-8f);
            slog += lg;
            ssum += v;
            if (m < kLow)        slow  += v;   // wave-uniform branch
            if (m >= kHighStart) shigh += v;
        }
    }

    __shared__ vfloat4 sh[4][4][64];   // [wid][qty][lane] = 16 KB
    sh[wid][0][lane] = slog;
    sh[wid][1][lane] = ssum;
    sh[wid][2][lane] = slow;
    sh[wid][3][lane] = shigh;
    __syncthreads();

    if (wid == 0 && valid) {
        slog  = sh[0][0][lane] + sh[1][0][lane] + sh[2][0][lane] + sh[3][0][lane];
        ssum  = sh[0][1][lane] + sh[1][1][lane] + sh[2][1][lane] + sh[3][1][lane];
        slow  = sh[0][2][lane] + sh[1][2][lane] + sh[2][2][lane] + sh[3][2][lane];
        shigh = sh[0][3][lane] + sh[1][3][lane] + sh[2][3][lane] + sh[3][3][lane];

        const float gt = gate_temp[0];
        float sl[4]  = {slog.x, slog.y, slog.z, slog.w};
        float ss[4]  = {ssum.x, ssum.y, ssum.z, ssum.w};
        float lo[4]  = {slow.x, slow.y, slow.z, slow.w};
        float hi[4]  = {shigh.x, shigh.y, shigh.z, shigh.w};
        float g4[4];
        #pragma unroll
        for (int q = 0; q < 4; ++q) {
            const float geo   = hw_exp2(sl[q] * (1.0f / kM));
            const float arith = ss[q] * (1.0f / kM) + 1e-8f;
            float sf = geo * __builtin_amdgcn_rcpf(arith);
            sf = fminf(fmaxf(sf, 0.0f), 1.0f);
            const float low  = lo[q] * (1.0f / kLow);
            const float high = hi[q] * (1.0f / kHighCount);
            float tilt = low * __builtin_amdgcn_rcpf(low + high + 1e-8f);
            tilt = fminf(fmaxf(tilt, 0.0f), 1.0f);
            const float sfa = sf + (1.0f - sf) * fmaxf(tilt - 0.6f, 0.0f);
            g4[q] = fast_sigmoid(gt * (sfa - 0.5f));
        }
        vfloat4 o; o.x = g4[0]; o.y = g4[1]; o.z = g4[2]; o.w = g4[3];
        *reinterpret_cast<vfloat4*>(gate + (size_t)b * kT + t0) = o;
    }
}

// ---------------- Kernel B: dual PCEN scan + gated blend ---------------------
// One block per (b,m) row. 256 threads x 16 elements = 4096 >= 4000.
// IIR sm[t] = a*sm[t-1] + s*x[t], carry sm[-1] = x[0].
// Dual recurrence packed as float2 {ns, st} -> v_pk_fma_f32.
// Chunked affine scan (shuffle within wave + LDS across waves).
__global__ __launch_bounds__(256) void pcen_kernel(
    const float* __restrict__ mel,
    const float* __restrict__ ls_ns, const float* __restrict__ la_ns,
    const float* __restrict__ ld_ns, const float* __restrict__ lr_ns,
    const float* __restrict__ ls_st, const float* __restrict__ la_st,
    const float* __restrict__ ld_st, const float* __restrict__ lr_st,
    const float* __restrict__ gate,
    float* __restrict__ out,
    int b0)
{
    const int m = blockIdx.x;
    const int b = b0 + blockIdx.y;

    const float s_ns     = fminf(fmaxf(fast_sigmoid(ls_ns[m]), 0.05f), 0.3f);
    const float alpha_ns = fminf(fmaxf(fast_sigmoid(la_ns[m]), 0.9f), 0.999f);
    const float delta_ns = fminf(fmaxf(hw_exp2(ld_ns[m] * LOG2E), 0.5f), 5.0f);
    const float r_ns     = fminf(fmaxf(fast_sigmoid(lr_ns[m]), 0.05f), 0.25f);
    const float s_st     = fminf(fmaxf(fast_sigmoid(ls_st[m]), 0.05f), 0.3f);
    const float alpha_st = fminf(fmaxf(fast_sigmoid(la_st[m]), 0.9f), 0.999f);
    const float delta_st = fminf(fmaxf(hw_exp2(ld_st[m] * LOG2E), 0.001f), 0.1f);
    const float r_st     = fminf(fmaxf(fast_sigmoid(lr_st[m]), 0.05f), 0.25f);
    const float dr_ns = hw_exp2(r_ns * hw_log2(delta_ns));   // delta^r
    const float dr_st = hw_exp2(r_st * hw_log2(delta_st));

    const vfloat2 a2 = {1.0f - s_ns, 1.0f - s_st};
    const vfloat2 s2 = {s_ns, s_st};
    const vfloat2 d2 = {delta_ns, delta_st};
    const float man = -alpha_ns, mas = -alpha_st;

    const size_t rowoff = ((size_t)b * kM + m) * kT;
    const float* row = mel + rowoff;

    const int tid = threadIdx.x;
    const int t0  = tid * 16;
    const bool valid = (t0 < kT);   // tids 250..255 are identity lanes

    float x[16];
    if (valid) {
        const float4* p = reinterpret_cast<const float4*>(row + t0);
        #pragma unroll
        for (int q = 0; q < 4; ++q) {
            const float4 v = p[q];
            x[4*q+0] = v.x; x[4*q+1] = v.y; x[4*q+2] = v.z; x[4*q+3] = v.w;
        }
    } else {
        #pragma unroll
        for (int k = 0; k < 16; ++k) x[k] = 0.0f;
    }

    __shared__ float sv0;
    if (tid == 0) sv0 = x[0];

    // local chunk transform: v -> A*v + B over 16 elements; A = a^16
    vfloat2 Av = {1.0f, 1.0f}, Bv = {0.0f, 0.0f};
    if (valid) {
        #pragma unroll
        for (int k = 0; k < 16; ++k) {
            Bv = a2 * Bv + s2 * x[k];          // v_pk_fma_f32
        }
        const vfloat2 p2 = a2 * a2;
        const vfloat2 p4 = p2 * p2;
        const vfloat2 p8 = p4 * p4;
        Av = p8 * p8;
    }

    const int lane = tid & 63;
    const int wid  = tid >> 6;

    // inclusive Hillis-Steele composition scan within wave
    #pragma unroll
    for (int d = 1; d < 64; d <<= 1) {
        const float qAn = __shfl_up(Av.x, d);
        const float qAs = __shfl_up(Av.y, d);
        const float qBn = __shfl_up(Bv.x, d);
        const float qBs = __shfl_up(Bv.y, d);
        if (lane >= d) {
            const vfloat2 qA = {qAn, qAs};
            const vfloat2 qB = {qBn, qBs};
            Bv = Av * qB + Bv;
            Av = Av * qA;
        }
    }

    __shared__ vfloat2 wA[4], wB[4];
    if (lane == 63) { wA[wid] = Av; wB[wid] = Bv; }
    __syncthreads();

    // exclusive within wave
    vfloat2 eA, eB;
    eA.x = __shfl_up(Av.x, 1); eA.y = __shfl_up(Av.y, 1);
    eB.x = __shfl_up(Bv.x, 1); eB.y = __shfl_up(Bv.y, 1);
    if (lane == 0) { eA = (vfloat2){1.0f, 1.0f}; eB = (vfloat2){0.0f, 0.0f}; }

    // composition of all preceding waves (at most 3 iterations)
    vfloat2 pA = {1.0f, 1.0f}, pB = {0.0f, 0.0f};
    for (int j = 0; j < wid; ++j) {
        pB = wA[j] * pB + wB[j];
        pA = wA[j] * pA;
    }

    // carry into this chunk: sm value just before t0
    const vfloat2 v0 = {sv0, sv0};
    vfloat2 sm = eA * (pA * v0 + pB) + eB;

    if (valid) {
        float gv[16];
        const float4* gp = reinterpret_cast<const float4*>(gate + (size_t)b * kT + t0);
        #pragma unroll
        for (int q = 0; q < 4; ++q) {
            const float4 v = gp[q];
            gv[4*q+0] = v.x; gv[4*q+1] = v.y; gv[4*q+2] = v.z; gv[4*q+3] = v.w;
        }

        float res[16];
        #pragma unroll
        for (int k = 0; k < 16; ++k) {
            const float xv = x[k];
            sm = a2 * sm + s2 * xv;            // v_pk_fma_f32
            vfloat2 g2;
            g2.x = hw_exp2(man * hw_log2(sm.x + EPSF));
            g2.y = hw_exp2(mas * hw_log2(sm.y + EPSF));
            const vfloat2 u2 = g2 * xv + d2;   // v_pk_fma_f32
            const float on = hw_exp2(r_ns * hw_log2(u2.x)) - dr_ns;
            const float os = hw_exp2(r_st * hw_log2(u2.y)) - dr_st;
            res[k] = fmaf(gv[k], os - on, on);
        }

        // plain cached stores: L2 assembles full lines (nt caused 2.7x write amp)
        float4* op = reinterpret_cast<float4*>(out + rowoff + t0);
        #pragma unroll
        for (int q = 0; q < 4; ++q) {
            float4 v;
            v.x = res[4*q+0]; v.y = res[4*q+1]; v.z = res[4*q+2]; v.w = res[4*q+3];
            op[q] = v;
        }
    }
}

extern "C" void kernel_launch(void* const* d_in, const int* in_sizes, int n_in,
                              void* d_out, int out_size, void* d_ws, size_t ws_size,
                              hipStream_t stream)
{
    const float* mel       = (const float*)d_in[0];
    const float* ls_ns     = (const float*)d_in[1];
    const float* la_ns     = (const float*)d_in[2];
    const float* ld_ns     = (const float*)d_in[3];
    const float* lr_ns     = (const float*)d_in[4];
    const float* ls_st     = (const float*)d_in[5];
    const float* la_st     = (const float*)d_in[6];
    const float* ld_st     = (const float*)d_in[7];
    const float* lr_st     = (const float*)d_in[8];
    const float* gate_temp = (const float*)d_in[9];
    float* out  = (float*)d_out;
    float* gate = (float*)d_ws;   // kB*kT floats = 1.02 MB scratch

    // Phase over b so pcen's mel re-read hits L3 (41 MB working set / phase).
    for (int p = 0; p < kPhases; ++p) {
        const int b0 = p * kBPhase;
        dim3 gA(16, kBPhase);
        gate_kernel<<<gA, 256, 0, stream>>>(mel, gate_temp, gate, b0);
        dim3 gB(kM, kBPhase);
        pcen_kernel<<<gB, 256, 0, stream>>>(mel, ls_ns, la_ns, ld_ns, lr_ns,
                                            ls_st, la_st, ld_st, lr_st, gate, out, b0);
    }
}

// Round 6
// 183.661 us; speedup vs baseline: 1.0554x; 1.0554x over previous
//
#include <hip/hip_runtime.h>
#include <math.h>

static constexpr int kM = 80;
static constexpr int kT = 4000;
static constexpr int kB = 64;
static constexpr int kLow = kM / 3;                 // 26
static constexpr int kHighStart = 2 * kM / 3;       // 53
static constexpr int kHighCount = kM - kHighStart;  // 27
#define EPSF 1e-6f
#define LOG2E 1.4426950408889634f

typedef float vfloat4 __attribute__((ext_vector_type(4)));
typedef float vfloat2 __attribute__((ext_vector_type(2)));

// HW transcendentals: v_exp_f32 computes 2^x, v_log_f32 computes log2(x)
__device__ __forceinline__ float hw_exp2(float x) { return __builtin_amdgcn_exp2f(x); }
__device__ __forceinline__ float hw_log2(float x) { return __builtin_amdgcn_logf(x); }

__device__ __forceinline__ float fast_sigmoid(float x) {
    return __builtin_amdgcn_rcpf(1.0f + hw_exp2(-x * LOG2E));
}

// ---------------- Kernel A: gate[b,t] from cross-channel reductions ----------
// Block = 256 thr (4 waves); wave w sums channels [20w,20w+20); lane = 4 cols
// via float4. Cross-wave reduce in LDS; wave 0 finalizes. grid (16, kB) = 1024
// blocks -> 4 blocks/CU, 16 waves/CU.
__global__ __launch_bounds__(256) void gate_kernel(
    const float* __restrict__ mel,
    const float* __restrict__ gate_temp,
    float* __restrict__ gate)
{
    const int lane = threadIdx.x & 63;
    const int wid  = threadIdx.x >> 6;
    const int b    = blockIdx.y;
    const int t0   = blockIdx.x * 256 + lane * 4;
    const bool valid = (t0 < kT);

    const float* base = mel + (size_t)b * kM * kT + t0;

    vfloat4 slog = {0.f,0.f,0.f,0.f}, ssum = {0.f,0.f,0.f,0.f};
    vfloat4 slow = {0.f,0.f,0.f,0.f}, shigh = {0.f,0.f,0.f,0.f};

    const int m0 = wid * 20;
    if (valid) {
        #pragma unroll
        for (int j = 0; j < 20; ++j) {
            const int m = m0 + j;
            const vfloat4 v = *reinterpret_cast<const vfloat4*>(base + (size_t)m * kT);
            vfloat4 lg;
            lg.x = hw_log2(v.x + 1e-8f); lg.y = hw_log2(v.y + 1e-8f);
            lg.z = hw_log2(v.z + 1e-8f); lg.w = hw_log2(v.w + 1e-8f);
            slog += lg;
            ssum += v;
            if (m < kLow)        slow  += v;   // wave-uniform branch
            if (m >= kHighStart) shigh += v;
        }
    }

    __shared__ vfloat4 sh[4][4][64];   // [wid][qty][lane] = 16 KB
    sh[wid][0][lane] = slog;
    sh[wid][1][lane] = ssum;
    sh[wid][2][lane] = slow;
    sh[wid][3][lane] = shigh;
    __syncthreads();

    if (wid == 0 && valid) {
        slog  = sh[0][0][lane] + sh[1][0][lane] + sh[2][0][lane] + sh[3][0][lane];
        ssum  = sh[0][1][lane] + sh[1][1][lane] + sh[2][1][lane] + sh[3][1][lane];
        slow  = sh[0][2][lane] + sh[1][2][lane] + sh[2][2][lane] + sh[3][2][lane];
        shigh = sh[0][3][lane] + sh[1][3][lane] + sh[2][3][lane] + sh[3][3][lane];

        const float gt = gate_temp[0];
        float sl[4]  = {slog.x, slog.y, slog.z, slog.w};
        float ss[4]  = {ssum.x, ssum.y, ssum.z, ssum.w};
        float lo[4]  = {slow.x, slow.y, slow.z, slow.w};
        float hi[4]  = {shigh.x, shigh.y, shigh.z, shigh.w};
        float g4[4];
        #pragma unroll
        for (int q = 0; q < 4; ++q) {
            const float geo   = hw_exp2(sl[q] * (1.0f / kM));
            const float arith = ss[q] * (1.0f / kM) + 1e-8f;
            float sf = geo * __builtin_amdgcn_rcpf(arith);
            sf = fminf(fmaxf(sf, 0.0f), 1.0f);
            const float low  = lo[q] * (1.0f / kLow);
            const float high = hi[q] * (1.0f / kHighCount);
            float tilt = low * __builtin_amdgcn_rcpf(low + high + 1e-8f);
            tilt = fminf(fmaxf(tilt, 0.0f), 1.0f);
            const float sfa = sf + (1.0f - sf) * fmaxf(tilt - 0.6f, 0.0f);
            g4[q] = fast_sigmoid(gt * (sfa - 0.5f));
        }
        vfloat4 o; o.x = g4[0]; o.y = g4[1]; o.z = g4[2]; o.w = g4[3];
        *reinterpret_cast<vfloat4*>(gate + (size_t)b * kT + t0) = o;
    }
}

// ---------------- Kernel B: dual PCEN scan + gated blend ---------------------
// One block per (b,m) row. 256 threads x 16 elements = 4096 >= 4000.
// IIR sm[t] = a*sm[t-1] + s*x[t], carry sm[-1] = x[0].
// Dual recurrence packed as float2 {ns, st} -> v_pk_fma_f32.
// Chunked affine scan (shuffle within wave + LDS across waves).
// Gate loads issued BEFORE the scan so their latency hides under it.
__global__ __launch_bounds__(256, 8) void pcen_kernel(
    const float* __restrict__ mel,
    const float* __restrict__ ls_ns, const float* __restrict__ la_ns,
    const float* __restrict__ ld_ns, const float* __restrict__ lr_ns,
    const float* __restrict__ ls_st, const float* __restrict__ la_st,
    const float* __restrict__ ld_st, const float* __restrict__ lr_st,
    const float* __restrict__ gate,
    float* __restrict__ out)
{
    const int m = blockIdx.x;
    const int b = blockIdx.y;

    const float s_ns     = fminf(fmaxf(fast_sigmoid(ls_ns[m]), 0.05f), 0.3f);
    const float alpha_ns = fminf(fmaxf(fast_sigmoid(la_ns[m]), 0.9f), 0.999f);
    const float delta_ns = fminf(fmaxf(hw_exp2(ld_ns[m] * LOG2E), 0.5f), 5.0f);
    const float r_ns     = fminf(fmaxf(fast_sigmoid(lr_ns[m]), 0.05f), 0.25f);
    const float s_st     = fminf(fmaxf(fast_sigmoid(ls_st[m]), 0.05f), 0.3f);
    const float alpha_st = fminf(fmaxf(fast_sigmoid(la_st[m]), 0.9f), 0.999f);
    const float delta_st = fminf(fmaxf(hw_exp2(ld_st[m] * LOG2E), 0.001f), 0.1f);
    const float r_st     = fminf(fmaxf(fast_sigmoid(lr_st[m]), 0.05f), 0.25f);
    const float dr_ns = hw_exp2(r_ns * hw_log2(delta_ns));   // delta^r
    const float dr_st = hw_exp2(r_st * hw_log2(delta_st));

    const vfloat2 a2 = {1.0f - s_ns, 1.0f - s_st};
    const vfloat2 s2 = {s_ns, s_st};
    const vfloat2 d2 = {delta_ns, delta_st};
    const float man = -alpha_ns, mas = -alpha_st;

    const size_t rowoff = ((size_t)b * kM + m) * kT;
    const float* row = mel + rowoff;

    const int tid = threadIdx.x;
    const int t0  = tid * 16;
    const bool valid = (t0 < kT);   // tids 250..255 are identity lanes

    float x[16];
    float gv[16];
    if (valid) {
        const float4* p = reinterpret_cast<const float4*>(row + t0);
        #pragma unroll
        for (int q = 0; q < 4; ++q) {
            const float4 v = p[q];
            x[4*q+0] = v.x; x[4*q+1] = v.y; x[4*q+2] = v.z; x[4*q+3] = v.w;
        }
        // prefetch gate now; latency overlaps the scan below
        const float4* gp = reinterpret_cast<const float4*>(gate + (size_t)b * kT + t0);
        #pragma unroll
        for (int q = 0; q < 4; ++q) {
            const float4 v = gp[q];
            gv[4*q+0] = v.x; gv[4*q+1] = v.y; gv[4*q+2] = v.z; gv[4*q+3] = v.w;
        }
    } else {
        #pragma unroll
        for (int k = 0; k < 16; ++k) { x[k] = 0.0f; gv[k] = 0.0f; }
    }

    __shared__ float sv0;
    if (tid == 0) sv0 = x[0];

    // local chunk transform: v -> A*v + B over 16 elements; A = a^16
    vfloat2 Av = {1.0f, 1.0f}, Bv = {0.0f, 0.0f};
    if (valid) {
        #pragma unroll
        for (int k = 0; k < 16; ++k) {
            Bv = a2 * Bv + s2 * x[k];          // v_pk_fma_f32
        }
        const vfloat2 p2 = a2 * a2;
        const vfloat2 p4 = p2 * p2;
        const vfloat2 p8 = p4 * p4;
        Av = p8 * p8;
    }

    const int lane = tid & 63;
    const int wid  = tid >> 6;

    // inclusive Hillis-Steele composition scan within wave
    #pragma unroll
    for (int d = 1; d < 64; d <<= 1) {
        const float qAn = __shfl_up(Av.x, d);
        const float qAs = __shfl_up(Av.y, d);
        const float qBn = __shfl_up(Bv.x, d);
        const float qBs = __shfl_up(Bv.y, d);
        if (lane >= d) {
            const vfloat2 qA = {qAn, qAs};
            const vfloat2 qB = {qBn, qBs};
            Bv = Av * qB + Bv;
            Av = Av * qA;
        }
    }

    __shared__ vfloat2 wA[4], wB[4];
    if (lane == 63) { wA[wid] = Av; wB[wid] = Bv; }
    __syncthreads();

    // exclusive within wave
    vfloat2 eA, eB;
    eA.x = __shfl_up(Av.x, 1); eA.y = __shfl_up(Av.y, 1);
    eB.x = __shfl_up(Bv.x, 1); eB.y = __shfl_up(Bv.y, 1);
    if (lane == 0) { eA = (vfloat2){1.0f, 1.0f}; eB = (vfloat2){0.0f, 0.0f}; }

    // composition of all preceding waves (at most 3 iterations)
    vfloat2 pA = {1.0f, 1.0f}, pB = {0.0f, 0.0f};
    for (int j = 0; j < wid; ++j) {
        pB = wA[j] * pB + wB[j];
        pA = wA[j] * pA;
    }

    // carry into this chunk: sm value just before t0
    const vfloat2 v0 = {sv0, sv0};
    vfloat2 sm = eA * (pA * v0 + pB) + eB;

    if (valid) {
        float res[16];
        #pragma unroll
        for (int k = 0; k < 16; ++k) {
            const float xv = x[k];
            sm = a2 * sm + s2 * xv;            // v_pk_fma_f32
            vfloat2 g2;
            g2.x = hw_exp2(man * hw_log2(sm.x + EPSF));
            g2.y = hw_exp2(mas * hw_log2(sm.y + EPSF));
            const vfloat2 u2 = g2 * xv + d2;   // v_pk_fma_f32
            const float on = hw_exp2(r_ns * hw_log2(u2.x)) - dr_ns;
            const float os = hw_exp2(r_st * hw_log2(u2.y)) - dr_st;
            res[k] = fmaf(gv[k], os - on, on);
        }

        // plain cached stores: L2 assembles full lines (nt caused 2.7x write amp)
        float4* op = reinterpret_cast<float4*>(out + rowoff + t0);
        #pragma unroll
        for (int q = 0; q < 4; ++q) {
            float4 v;
            v.x = res[4*q+0]; v.y = res[4*q+1]; v.z = res[4*q+2]; v.w = res[4*q+3];
            op[q] = v;
        }
    }
}

extern "C" void kernel_launch(void* const* d_in, const int* in_sizes, int n_in,
                              void* d_out, int out_size, void* d_ws, size_t ws_size,
                              hipStream_t stream)
{
    const float* mel       = (const float*)d_in[0];
    const float* ls_ns     = (const float*)d_in[1];
    const float* la_ns     = (const float*)d_in[2];
    const float* ld_ns     = (const float*)d_in[3];
    const float* lr_ns     = (const float*)d_in[4];
    const float* ls_st     = (const float*)d_in[5];
    const float* la_st     = (const float*)d_in[6];
    const float* ld_st     = (const float*)d_in[7];
    const float* lr_st     = (const float*)d_in[8];
    const float* gate_temp = (const float*)d_in[9];
    float* out  = (float*)d_out;
    float* gate = (float*)d_ws;   // kB*kT floats = 1.02 MB scratch

    dim3 gA(16, kB);                     // 1024 blocks, 4 waves each
    gate_kernel<<<gA, 256, 0, stream>>>(mel, gate_temp, gate);

    dim3 gB(kM, kB);                     // 5120 blocks, one (b,m) row each
    pcen_kernel<<<gB, 256, 0, stream>>>(mel, ls_ns, la_ns, ld_ns, lr_ns,
                                        ls_st, la_st, ld_st, lr_st, gate, out);
}